// Round 1
// 269.544 us; speedup vs baseline: 1.0923x; 1.0923x over previous
//
#include <hip/hip_runtime.h>
#include <hip/hip_bf16.h>

#define TDIM 2048
#define NDIM 2048
#define BHN  8
#define LD   2048

typedef __attribute__((ext_vector_type(8))) short bf16x8;
typedef __attribute__((ext_vector_type(4))) float f32x4;
typedef unsigned short us;

static __device__ __forceinline__ us f2bf(float x) {
  union { __hip_bfloat16 h; us u; } cv;
  cv.h = __float2bfloat16(x);
  return cv.u;
}

// ---------------- RoPE + bf16 cast ----------------
__global__ __launch_bounds__(256) void rope_kernel(const float* __restrict__ Q,
                                                   us* __restrict__ QR,
                                                   int total8) {
  int idx = blockIdx.x * blockDim.x + threadIdx.x;
  if (idx >= total8) return;
  long base = (long)idx * 8;
  int n = (int)(base & (NDIM - 1));
  int t = (int)((base >> 11) & (TDIM - 1));
  const float4* p = reinterpret_cast<const float4*>(Q + base);
  float4 v0 = p[0], v1 = p[1];
  float q[8] = {v0.x, v0.y, v0.z, v0.w, v1.x, v1.y, v1.z, v1.w};
  us r[8];
  float tf = (float)t;
#pragma unroll
  for (int pr = 0; pr < 4; ++pr) {
    int nn = n + pr * 2;
    float freq = __builtin_exp2f((float)nn * (-1.0f / 128.0f)) * 0.15915494309189535f;
    float ph = tf * freq;
    ph = ph - __builtin_floorf(ph);
    float c = __builtin_amdgcn_cosf(ph);
    float s = __builtin_amdgcn_sinf(ph);
    float e = q[2 * pr], o = q[2 * pr + 1];
    r[2 * pr]     = f2bf(e * c - o * s);
    r[2 * pr + 1] = f2bf(o * c + e * s);
  }
  union { us usv[8]; bf16x8 v; } pk;
#pragma unroll
  for (int i = 0; i < 8; ++i) pk.usv[i] = r[i];
  *reinterpret_cast<bf16x8*>(QR + base) = pk.v;
}

// ---------------- V transpose + bf16 cast ----------------
__global__ __launch_bounds__(256) void vtrans_kernel(const float* __restrict__ V,
                                                     us* __restrict__ VT) {
  __shared__ float tile[32][33];
  int bh = blockIdx.z;
  int n0 = blockIdx.x * 32, t0 = blockIdx.y * 32;
  const float* Vp = V + (long)bh * TDIM * NDIM;
  us* Tp = VT + (long)bh * TDIM * NDIM;
  int tx = threadIdx.x, ty = threadIdx.y;
#pragma unroll
  for (int i = 0; i < 4; ++i)
    tile[ty + i * 8][tx] = Vp[(long)(t0 + ty + i * 8) * NDIM + n0 + tx];
  __syncthreads();
#pragma unroll
  for (int i = 0; i < 4; ++i)
    Tp[(long)(n0 + ty + i * 8) * TDIM + t0 + tx] = f2bf(tile[tx][ty + i * 8]);
}

// ---------------- 256x256 8-phase NT GEMM (BK=64, 8 waves, T2+T3+T4+T5) ----------------
// PASS 0: S = causal_strict(A * A^T), bf16 out.
//   grid = 36*nh lower-tri tiles, kts=32. head = bid % nh -> one head per XCD.
// PASS 1: C = S * VT^T, f32 out. PERSISTENT PAIRED blocks: grid = 32*nh,
//   each block does segment 0 (rt=7-cls, heavy) then segment 1 (rt=cls, light)
//   at the same ct -> exactly 36 K-steps/block, B-panel L2-warm across segs.
template <int PASS>
__global__ __launch_bounds__(512, 2) void gemm256(
    const us* __restrict__ Abase, const us* __restrict__ Bbase,
    void* __restrict__ Cbase, int nh) {
  extern __shared__ us lds[];  // [A buf0 16K][A buf1 16K][B buf0 16K][B buf1 16K] elems
  int bid = (int)blockIdx.x;
  int head, rt = 0, ct, kts = 32, cls = 0;
  if constexpr (PASS == 0) {
    head = bid % nh;             // bid%8 -> XCD: one head per XCD L2
    int tri = bid / nh;
    rt = 0;
    while ((rt + 1) * (rt + 2) / 2 <= tri) ++rt;
    ct = tri - rt * (rt + 1) / 2;
    kts = 32;
  } else {
    head = bid % nh;             // one head per XCD L2
    int rem = bid / nh;
    ct = rem & 7;
    cls = rem >> 3;              // 0..3 pair class
  }
  const us* A = Abase + (long)head * TDIM * LD;
  const us* B = Bbase + (long)head * TDIM * LD;
  const int tid = (int)threadIdx.x;
  const int lane = tid & 63, wid = tid >> 6;
  const int wr = wid >> 2, wc = wid & 3;          // 2 x 4 waves; wave tile 128 x 64
  const int l15 = lane & 15, l4 = lane >> 4;

  f32x4 acc[8][4];
  const int NSEG = (PASS == 0) ? 1 : 2;

#pragma unroll 1
  for (int seg = 0; seg < NSEG; ++seg) {
    if constexpr (PASS == 1) {
      rt = seg ? cls : 7 - cls;   // heavy first; light reads B-prefix (L2-hot)
      kts = (rt + 1) * 4;
    }
    const int row0 = rt * 256, col0 = ct * 256;

#pragma unroll
    for (int m = 0; m < 8; ++m)
#pragma unroll
      for (int n = 0; n < 4; ++n) acc[m][n] = (f32x4){0.f, 0.f, 0.f, 0.f};

    // stage one half-tile (128 rows x 64 cols bf16): 2 x global_load_lds(16B)/thread.
    // LDS dest linear; source col pre-swizzled (chunk_log = chunk_phys ^ (row&7)).
    auto stage = [&](int half /*0=A0,1=A1,2=B0,3=B1*/, int t) {
      const us* g0 = (half < 2) ? A : B;
      const int tr0 = (half < 2) ? row0 : col0;
      const int h = half & 1;
      us* lb = lds + ((half < 2) ? 0 : 32768) + (t & 1) * 16384;
      const int k0 = t * 64;
#pragma unroll
      for (int r = 0; r < 2; ++r) {
        int off = r * 512 + tid;          // 16B-unit index within the 16KB half
        int row = off >> 3;
        int ch = off & 7;
        int chl = ch ^ (row & 7);
        const us* g = g0 + (long)(tr0 + h * 128 + row) * LD + (k0 + chl * 8);
        us* l = lb + h * 8192 + off * 8;  // linear per-lane dest
        __builtin_amdgcn_global_load_lds(
            (const __attribute__((address_space(1))) unsigned int*)g,
            (__attribute__((address_space(3))) unsigned int*)l, 16, 0, 0);
      }
    };
    auto ldA = [&](int b, int m, int ks) -> bf16x8 {
      int row = wr * 128 + m * 16 + l15;
      int ch = (ks * 4 + l4) ^ (row & 7);
      return *reinterpret_cast<const bf16x8*>(lds + b * 16384 + row * 64 + ch * 8);
    };
    auto ldB = [&](int b, int n, int ks) -> bf16x8 {
      int row = wc * 64 + n * 16 + l15;
      int ch = (ks * 4 + l4) ^ (row & 7);
      return *reinterpret_cast<const bf16x8*>(lds + 32768 + b * 16384 + row * 64 + ch * 8);
    };

    // Prologue: tile0 fully, tile1 B-halves; wait tile0 landed (4 insts outstanding).
    stage(0, 0); stage(1, 0); stage(2, 0); stage(3, 0);
    if (1 < kts) { stage(2, 1); stage(3, 1); }
    asm volatile("s_waitcnt vmcnt(4)" ::: "memory");
    __builtin_amdgcn_s_barrier();
    __builtin_amdgcn_sched_barrier(0);

    bf16x8 af[4][2], bfr[4][2];
    for (int t = 0; t < kts; ++t) {
      const int b = t & 1;
      // ---- phase 1: read A m0-3 + B n0-1; stage A-half0(t+1); MFMA q(0,0) ----
#pragma unroll
      for (int m = 0; m < 4; ++m) { af[m][0] = ldA(b, m, 0); af[m][1] = ldA(b, m, 1); }
#pragma unroll
      for (int n = 0; n < 2; ++n) { bfr[n][0] = ldB(b, n, 0); bfr[n][1] = ldB(b, n, 1); }
      if (t + 1 < kts) stage(0, t + 1);
      __builtin_amdgcn_s_barrier();
      asm volatile("s_waitcnt lgkmcnt(0)" ::: "memory");
      __builtin_amdgcn_sched_barrier(0);
      __builtin_amdgcn_s_setprio(1);
#pragma unroll
      for (int m = 0; m < 4; ++m)
#pragma unroll
        for (int n = 0; n < 2; ++n)
#pragma unroll
          for (int ks = 0; ks < 2; ++ks)
            acc[m][n] = __builtin_amdgcn_mfma_f32_16x16x32_bf16(af[m][ks], bfr[n][ks], acc[m][n], 0, 0, 0);
      __builtin_amdgcn_s_setprio(0);
      __builtin_amdgcn_sched_barrier(0);
      __builtin_amdgcn_s_barrier();
      // ---- phase 2: read B n2-3; stage A-half1(t+1); MFMA q(0,1) ----
#pragma unroll
      for (int n = 2; n < 4; ++n) { bfr[n][0] = ldB(b, n, 0); bfr[n][1] = ldB(b, n, 1); }
      if (t + 1 < kts) stage(1, t + 1);
      __builtin_amdgcn_s_barrier();
      asm volatile("s_waitcnt lgkmcnt(0)" ::: "memory");
      __builtin_amdgcn_sched_barrier(0);
      __builtin_amdgcn_s_setprio(1);
#pragma unroll
      for (int m = 0; m < 4; ++m)
#pragma unroll
        for (int n = 2; n < 4; ++n)
#pragma unroll
          for (int ks = 0; ks < 2; ++ks)
            acc[m][n] = __builtin_amdgcn_mfma_f32_16x16x32_bf16(af[m][ks], bfr[n][ks], acc[m][n], 0, 0, 0);
      __builtin_amdgcn_s_setprio(0);
      __builtin_amdgcn_sched_barrier(0);
      __builtin_amdgcn_s_barrier();
      // ---- phase 3: read A m4-7; stage B-half0(t+2); MFMA q(1,0) ----
#pragma unroll
      for (int m = 0; m < 4; ++m) { af[m][0] = ldA(b, m + 4, 0); af[m][1] = ldA(b, m + 4, 1); }
      if (t + 2 < kts) stage(2, t + 2);
      __builtin_amdgcn_s_barrier();
      asm volatile("s_waitcnt lgkmcnt(0)" ::: "memory");
      __builtin_amdgcn_sched_barrier(0);
      __builtin_amdgcn_s_setprio(1);
#pragma unroll
      for (int m = 0; m < 4; ++m)
#pragma unroll
        for (int n = 0; n < 2; ++n)
#pragma unroll
          for (int ks = 0; ks < 2; ++ks)
            acc[m + 4][n] = __builtin_amdgcn_mfma_f32_16x16x32_bf16(af[m][ks], bfr[n][ks], acc[m + 4][n], 0, 0, 0);
      __builtin_amdgcn_s_setprio(0);
      __builtin_amdgcn_sched_barrier(0);
      __builtin_amdgcn_s_barrier();
      // ---- phase 4: stage B-half1(t+2); MFMA q(1,1); counted vmcnt; barrier ----
      if (t + 2 < kts) stage(3, t + 2);
      __builtin_amdgcn_s_setprio(1);
#pragma unroll
      for (int m = 0; m < 4; ++m)
#pragma unroll
        for (int n = 2; n < 4; ++n)
#pragma unroll
          for (int ks = 0; ks < 2; ++ks)
            acc[m + 4][n] = __builtin_amdgcn_mfma_f32_16x16x32_bf16(af[m][ks], bfr[n][ks], acc[m + 4][n], 0, 0, 0);
      __builtin_amdgcn_s_setprio(0);
      if (t + 2 < kts) { asm volatile("s_waitcnt vmcnt(4)" ::: "memory"); }  // tile t+1 landed; B(t+2) in flight
      else             { asm volatile("s_waitcnt vmcnt(0)" ::: "memory"); }  // segment drain
      __builtin_amdgcn_sched_barrier(0);
      __builtin_amdgcn_s_barrier();
      __builtin_amdgcn_sched_barrier(0);
    }

    // Epilogue. C/D layout: col=lane&15, row=(lane>>4)*4+j.
    if constexpr (PASS == 0) {
      us* C = (us*)Cbase + (long)head * TDIM * LD;
      const bool diag = (rt == ct);
#pragma unroll
      for (int m = 0; m < 8; ++m) {
        int r0 = row0 + wr * 128 + m * 16 + l4 * 4;
#pragma unroll
        for (int n = 0; n < 4; ++n) {
          int cc = col0 + wc * 64 + n * 16 + l15;
#pragma unroll
          for (int j = 0; j < 4; ++j) {
            int tt = r0 + j;
            float v = acc[m][n][j];
            if (diag && cc >= tt) v = 0.0f;  // strict causal
            C[(long)tt * LD + cc] = f2bf(v);
          }
        }
      }
    } else {
      float* C = (float*)Cbase + (long)head * TDIM * LD;
#pragma unroll
      for (int m = 0; m < 8; ++m) {
        int r0 = row0 + wr * 128 + m * 16 + l4 * 4;
#pragma unroll
        for (int n = 0; n < 4; ++n) {
          int cc = col0 + wc * 64 + n * 16 + l15;
#pragma unroll
          for (int j = 0; j < 4; ++j)
            C[(long)(r0 + j) * LD + cc] = acc[m][n][j];
        }
      }
    }
  }  // seg loop
}

extern "C" void kernel_launch(void* const* d_in, const int* in_sizes, int n_in,
                              void* d_out, int out_size, void* d_ws, size_t ws_size,
                              hipStream_t stream) {
  const float* Q = (const float*)d_in[0];
  const float* V = (const float*)d_in[1];
  float* Out = (float*)d_out;
  char* ws = (char*)d_ws;
  const long TN = (long)TDIM * NDIM;
  const size_t BUF = (size_t)BHN * TN * 2;   // 64 MiB
  const size_t PERBH = (size_t)TN * 2;       // 8 MiB
  const int SHMEM = 131072;                  // 128 KiB dynamic LDS

  hipFuncSetAttribute(reinterpret_cast<const void*>(&gemm256<0>),
                      hipFuncAttributeMaxDynamicSharedMemorySize, SHMEM);
  hipFuncSetAttribute(reinterpret_cast<const void*>(&gemm256<1>),
                      hipFuncAttributeMaxDynamicSharedMemorySize, SHMEM);

  if (ws_size >= 3 * BUF) {
    us* QRb = (us*)ws;
    us* VbT = (us*)(ws + BUF);
    us* S   = (us*)(ws + 2 * BUF);
    int total8 = (int)(BHN * TN / 8);
    rope_kernel<<<dim3(total8 / 256), dim3(256), 0, stream>>>(Q, QRb, total8);
    vtrans_kernel<<<dim3(64, 64, 8), dim3(32, 8), 0, stream>>>(V, VbT);
    gemm256<0><<<dim3(36 * BHN), dim3(512), SHMEM, stream>>>(QRb, QRb, S, BHN);
    gemm256<1><<<dim3(32 * BHN), dim3(512), SHMEM, stream>>>(S, VbT, Out, BHN);
  } else {
    // per-head fallback (min ~24 MiB ws)
    us* QR0 = (us*)ws;
    us* VT0 = (us*)(ws + PERBH);
    us* S0  = (us*)(ws + 2 * PERBH);
    int total8 = (int)(TN / 8);
    for (int bh = 0; bh < BHN; ++bh) {
      rope_kernel<<<dim3(total8 / 256), dim3(256), 0, stream>>>(Q + bh * TN, QR0, total8);
      vtrans_kernel<<<dim3(64, 64, 1), dim3(32, 8), 0, stream>>>(V + bh * TN, VT0);
      gemm256<0><<<dim3(36), dim3(512), SHMEM, stream>>>(QR0, QR0, S0, 1);
      gemm256<1><<<dim3(32), dim3(512), SHMEM, stream>>>(S0, VT0, Out + bh * TN, 1);
    }
  }
}